// Round 3
// baseline (35.963 us; speedup 1.0000x reference)
//
#include <hip/hip_runtime.h>
#include <math.h>

#define DD 1024
#define BB 8192

__device__ __forceinline__ float softplus_f(float x) {
    // stable log1p(exp(x))
    return fmaxf(x, 0.0f) + log1pf(expf(-fabsf(x)));
}

// ---------------- kernel A: partials of t[j] = sum_i softplus(rho[i,j])*eps[i]
// 256 blocks = 16 colgroups x 16 rowgroups. Lanes span 64 consecutive columns
// -> fully coalesced 256B wave reads, rho fetched exactly once (4 MB).
// Partials land in ws[j*16 + rg]; k_u sums them (no atomics, no memset).
__global__ __launch_bounds__(256) void k_t(const float* __restrict__ rho,
                                           const float* __restrict__ eps,
                                           float* __restrict__ part) {
    const int tx = threadIdx.x, lane = tx & 63, w = tx >> 6;
    const int cg = blockIdx.x & 15, rg = blockIdx.x >> 4;
    const int j = cg * 64 + lane;
    const int rowbase = rg * 64 + w * 16;
    float acc = 0.f;
#pragma unroll
    for (int k = 0; k < 16; ++k) {
        int row = rowbase + k;
        acc += softplus_f(rho[row * DD + j]) * eps[row];
    }
    __shared__ float red[4][64];
    red[w][lane] = acc;
    __syncthreads();
    if (tx < 64) {
        float s = red[0][tx] + red[1][tx] + red[2][tx] + red[3][tx];
        part[(cg * 64 + tx) * 16 + rg] = s;
    }
}

// ---------------- kernel B: u[i] = mu[i] + sum_j softplus(rho[i,j]) * t[j] ----
// t[j] reconstituted from the 16 partials (4x float4, L2-resident).
__global__ __launch_bounds__(256) void k_u(const float* __restrict__ rho,
                                           const float* __restrict__ mu,
                                           const float* __restrict__ part,
                                           float* __restrict__ u) {
    int i  = blockIdx.x;      // 1024 blocks
    int tx = threadIdx.x;
    float acc = 0.f;
#pragma unroll
    for (int c = 0; c < 4; ++c) {
        int j = tx + c * 256;
        const float4* p4 = (const float4*)(part + j * 16);
        float4 a = p4[0], b = p4[1], cc = p4[2], dd = p4[3];
        float tj = ((a.x + a.y) + (a.z + a.w)) + ((b.x + b.y) + (b.z + b.w)) +
                   ((cc.x + cc.y) + (cc.z + cc.w)) + ((dd.x + dd.y) + (dd.z + dd.w));
        acc += softplus_f(rho[i * DD + j]) * tj;
    }
#pragma unroll
    for (int off = 32; off > 0; off >>= 1)
        acc += __shfl_down(acc, off, 64);
    __shared__ float red[4];
    int lane = tx & 63, w = tx >> 6;
    if (lane == 0) red[w] = acc;
    __syncthreads();
    if (tx == 0) u[i] = mu[i] + red[0] + red[1] + red[2] + red[3];
}

// ---------------- main: out[d,b] = relu(s1*FWHT(u*FWHT(s2*x_b))/1024) ---------

template <int CTRL>
__device__ __forceinline__ float dppmov(float x) {
    return __int_as_float(
        __builtin_amdgcn_mov_dpp(__float_as_int(x), CTRL, 0xF, 0xF, true));
}

// Position mapping: lane l (bits l0..l5), reg m (4 bits). p = 16*hi(l) + m with
//   h0=l0^l2  h1=l1^l2  h2=l2^l3  h3=l3  h4=l4  h5=l5
// so flipping position bits p4..p9 corresponds to lane XOR masks
//   1 (quad_perm), 2 (quad_perm), 7 (row_half_mirror), 15 (row_mirror), 16, 32.
__device__ __forceinline__ void fwht1024(float v[16], float sA, float sB,
                                         float sC, float sD, float sE, float sF) {
#pragma unroll
    for (int s = 1; s <= 8; s <<= 1) {
#pragma unroll
        for (int m = 0; m < 16; ++m)
            if ((m & s) == 0) {
                float a = v[m], b = v[m ^ s];
                v[m] = a + b;
                v[m ^ s] = a - b;
            }
    }
#pragma unroll
    for (int m = 0; m < 16; ++m) { float o = dppmov<0xB1>(v[m]);  v[m] = fmaf(v[m], sA, o); } // xor 1
#pragma unroll
    for (int m = 0; m < 16; ++m) { float o = dppmov<0x4E>(v[m]);  v[m] = fmaf(v[m], sB, o); } // xor 2
#pragma unroll
    for (int m = 0; m < 16; ++m) { float o = dppmov<0x141>(v[m]); v[m] = fmaf(v[m], sC, o); } // xor 7
#pragma unroll
    for (int m = 0; m < 16; ++m) { float o = dppmov<0x140>(v[m]); v[m] = fmaf(v[m], sD, o); } // xor 15
#pragma unroll
    for (int m = 0; m < 16; ++m) { float o = __shfl_xor(v[m], 16, 64); v[m] = fmaf(v[m], sE, o); } // xor 16
#pragma unroll
    for (int m = 0; m < 16; ++m) { float o = __shfl_xor(v[m], 32, 64); v[m] = fmaf(v[m], sF, o); } // xor 32
}

__device__ __forceinline__ unsigned bf16_rne(float f) {
    unsigned uu = __float_as_uint(f);
    return (uu + 0x7FFFu + ((uu >> 16) & 1u)) >> 16;
}

// 32 batches per block (full 128B output lines), 512 threads, 2 blocks/CU.
// Transpose tile holds bf16-packed PAIRS of batch rows -> same 16-"row" LDS
// swizzle geometry as the verified f32 version, at half the bytes (64 KB).
__global__ __launch_bounds__(512, 4) void k_main(const float* __restrict__ x,
                                                 const float* __restrict__ s1,
                                                 const float* __restrict__ s2,
                                                 const float* __restrict__ u,
                                                 float* __restrict__ out) {
    __shared__ unsigned tile[16 * 1024];   // 64 KB: 16 row-pairs, XOR-swizzled
    const int t    = threadIdx.x;
    const int lane = t & 63;
    const int wv   = t >> 6;               // 0..7, each wave owns 4 batch rows
    const int b0   = blockIdx.x * 32;      // 256 blocks

    const int l0 = lane & 1, l1 = (lane >> 1) & 1, l2 = (lane >> 2) & 1,
              l3 = (lane >> 3) & 1, l4 = (lane >> 4) & 1, l5 = (lane >> 5) & 1;
    const int hi = (l0 ^ l2) | ((l1 ^ l2) << 1) | ((l2 ^ l3) << 2) | (l3 << 3) |
                   (l4 << 4) | (l5 << 5);
    const int base = hi << 4;

    const float sA = (l0 ^ l2) ? -1.f : 1.f;
    const float sB = (l1 ^ l2) ? -1.f : 1.f;
    const float sC = (l2 ^ l3) ? -1.f : 1.f;
    const float sD = l3 ? -1.f : 1.f;
    const float sE = l4 ? -1.f : 1.f;
    const float sF = l5 ? -1.f : 1.f;

    float4 s2f[4], uf[4], s1f[4];
#pragma unroll
    for (int c = 0; c < 4; ++c) {
        s2f[c] = *(const float4*)(s2 + base + 4 * c);
        uf[c]  = *(const float4*)(u  + base + 4 * c);
        s1f[c] = *(const float4*)(s1 + base + 4 * c);
        const float kscale = 1.0f / 1024.0f;   // fold 1/D into s1
        s1f[c].x *= kscale; s1f[c].y *= kscale;
        s1f[c].z *= kscale; s1f[c].w *= kscale;
    }
    const int swz = (lane >> 1) & 15;

#pragma unroll
    for (int pp = 0; pp < 2; ++pp) {
        const int rA = wv * 4 + pp * 2;    // even row of the pair
        const int rp = rA >> 1;            // pair index 0..15
        const float* xr0 = x + (size_t)(b0 + rA) * DD + base;
        const float* xr1 = xr0 + DD;
        float va[16], vb[16];
#pragma unroll
        for (int c = 0; c < 4; ++c) {
            float4 xv0 = *(const float4*)(xr0 + 4 * c);
            float4 xv1 = *(const float4*)(xr1 + 4 * c);
            va[4 * c + 0] = xv0.x * s2f[c].x;  vb[4 * c + 0] = xv1.x * s2f[c].x;
            va[4 * c + 1] = xv0.y * s2f[c].y;  vb[4 * c + 1] = xv1.y * s2f[c].y;
            va[4 * c + 2] = xv0.z * s2f[c].z;  vb[4 * c + 2] = xv1.z * s2f[c].z;
            va[4 * c + 3] = xv0.w * s2f[c].w;  vb[4 * c + 3] = xv1.w * s2f[c].w;
        }
        fwht1024(va, sA, sB, sC, sD, sE, sF);
        fwht1024(vb, sA, sB, sC, sD, sE, sF);
#pragma unroll
        for (int c = 0; c < 4; ++c) {
            va[4 * c + 0] *= uf[c].x;  vb[4 * c + 0] *= uf[c].x;
            va[4 * c + 1] *= uf[c].y;  vb[4 * c + 1] *= uf[c].y;
            va[4 * c + 2] *= uf[c].z;  vb[4 * c + 2] *= uf[c].z;
            va[4 * c + 3] *= uf[c].w;  vb[4 * c + 3] *= uf[c].w;
        }
        fwht1024(va, sA, sB, sC, sD, sE, sF);
        fwht1024(vb, sA, sB, sC, sD, sE, sF);
        // relu + scale, pack two rows into one u32 per feature
        unsigned* trow = tile + rp * 1024;
        const int baseW = ((hi ^ ((rp >> 2) & 3)) << 4);
        const int sw2 = (swz ^ rp) & 15;
#pragma unroll
        for (int c = 0; c < 4; ++c) {
#pragma unroll
            for (int k = 0; k < 4; ++k) {
                const int idx = 4 * c + k;
                const float sc = (k == 0) ? s1f[c].x : (k == 1) ? s1f[c].y
                                 : (k == 2) ? s1f[c].z : s1f[c].w;
                float ya = fmaxf(va[idx] * sc, 0.f);
                float yb = fmaxf(vb[idx] * sc, 0.f);
                trow[baseW + (idx ^ sw2)] = bf16_rne(ya) | (bf16_rne(yb) << 16);
            }
        }
    }
    __syncthreads();

    // transposed store: per it, 8 threads cover one feature d's 32 batches
    // (full 128B line). Each thread: 2 packed pairs -> float4 (16B).
#pragma unroll
    for (int it = 0; it < 16; ++it) {
        const int d   = (t >> 3) + (it << 6);
        const int g   = t & 7;
        const int rp0 = g * 2, rp1 = rp0 + 1;
        const int h   = d >> 4;
        const int dl  = d & 15;
        const int h1 = (h >> 1) & 1, h2 = (h >> 2) & 1, h3 = (h >> 3) & 1,
                  h4 = (h >> 4) & 1;
        const int sw = (h1 ^ h2 ^ h3) | ((h2 ^ h3) << 1) | (h3 << 2) | (h4 << 3);
        unsigned p0 = tile[rp0 * 1024 + ((h ^ ((rp0 >> 2) & 3)) << 4) +
                           ((dl ^ sw ^ rp0) & 15)];
        unsigned p1 = tile[rp1 * 1024 + ((h ^ ((rp1 >> 2) & 3)) << 4) +
                           ((dl ^ sw ^ rp1) & 15)];
        float4 y;
        y.x = __uint_as_float(p0 << 16);
        y.y = __uint_as_float(p0 & 0xFFFF0000u);
        y.z = __uint_as_float(p1 << 16);
        y.w = __uint_as_float(p1 & 0xFFFF0000u);
        *(float4*)(out + (size_t)d * BB + b0 + g * 4) = y;
    }
}

extern "C" void kernel_launch(void* const* d_in, const int* in_sizes, int n_in,
                              void* d_out, int out_size, void* d_ws, size_t ws_size,
                              hipStream_t stream) {
    const float* x   = (const float*)d_in[0];
    const float* s1  = (const float*)d_in[1];
    const float* s2  = (const float*)d_in[2];
    const float* mu  = (const float*)d_in[3];
    const float* rho = (const float*)d_in[4];
    const float* eps = (const float*)d_in[5];
    // d_in[6] = H is unused: we apply it via fast Walsh-Hadamard transform.
    float* out = (float*)d_out;

    float* part = (float*)d_ws;      // [DD * 16] partials of t
    float* u    = part + DD * 16;    // [DD]

    k_t<<<256, 256, 0, stream>>>(rho, eps, part);
    k_u<<<DD, 256, 0, stream>>>(rho, mu, part, u);
    k_main<<<BB / 32, 512, 0, stream>>>(x, s1, s2, u, out);
}

// Round 6
// 34.790 us; speedup vs baseline: 1.0337x; 1.0337x over previous
//
#include <hip/hip_runtime.h>
#include <math.h>

#define DD 1024
#define BB 8192

__device__ __forceinline__ float softplus_f(float x) {
    return fmaxf(x, 0.0f) + log1pf(expf(-fabsf(x)));
}

// ---------------- kernel A: partials of t[j] = sum_i softplus(rho[i,j])*eps[i]
// 256 blocks = 16 colgroups x 16 rowgroups, fully coalesced, no atomics.
__global__ __launch_bounds__(256) void k_t(const float* __restrict__ rho,
                                           const float* __restrict__ eps,
                                           float* __restrict__ part) {
    const int tx = threadIdx.x, lane = tx & 63, w = tx >> 6;
    const int cg = blockIdx.x & 15, rg = blockIdx.x >> 4;
    const int j = cg * 64 + lane;
    const int rowbase = rg * 64 + w * 16;
    float acc = 0.f;
#pragma unroll
    for (int k = 0; k < 16; ++k) {
        int row = rowbase + k;
        acc += softplus_f(rho[row * DD + j]) * eps[row];
    }
    __shared__ float red[4][64];
    red[w][lane] = acc;
    __syncthreads();
    if (tx < 64) {
        float s = red[0][tx] + red[1][tx] + red[2][tx] + red[3][tx];
        part[(cg * 64 + tx) * 16 + rg] = s;
    }
}

// ---------------- kernel B: u[i] = mu[i] + sum_j softplus(rho[i,j]) * t[j] ----
__global__ __launch_bounds__(256) void k_u(const float* __restrict__ rho,
                                           const float* __restrict__ mu,
                                           const float* __restrict__ part,
                                           float* __restrict__ u) {
    int i  = blockIdx.x;      // 1024 blocks
    int tx = threadIdx.x;
    float acc = 0.f;
#pragma unroll
    for (int c = 0; c < 4; ++c) {
        int j = tx + c * 256;
        const float4* p4 = (const float4*)(part + j * 16);
        float4 a = p4[0], b = p4[1], cc = p4[2], dd = p4[3];
        float tj = ((a.x + a.y) + (a.z + a.w)) + ((b.x + b.y) + (b.z + b.w)) +
                   ((cc.x + cc.y) + (cc.z + cc.w)) + ((dd.x + dd.y) + (dd.z + dd.w));
        acc += softplus_f(rho[i * DD + j]) * tj;
    }
#pragma unroll
    for (int off = 32; off > 0; off >>= 1)
        acc += __shfl_down(acc, off, 64);
    __shared__ float red[4];
    int lane = tx & 63, w = tx >> 6;
    if (lane == 0) red[w] = acc;
    __syncthreads();
    if (tx == 0) u[i] = mu[i] + red[0] + red[1] + red[2] + red[3];
}

// ---------------- main: out[d,b] = relu(s1*FWHT(u*FWHT(s2*x_b))/1024) ---------

template <int CTRL>
__device__ __forceinline__ float dppmov(float x) {
    return __int_as_float(
        __builtin_amdgcn_mov_dpp(__float_as_int(x), CTRL, 0xF, 0xF, true));
}

// Position mapping: lane l (bits l0..l5), reg m. p = 16*hi(l) + m with
//   h0=l0^l2 h1=l1^l2 h2=l2^l3 h3=l3 h4=l4 h5=l5
// cross-lane stages = lane XOR masks {1,2,7,15,16,32}. (R1-R3 validated form.)
__device__ __forceinline__ void fwht1024(float v[16], float sA, float sB,
                                         float sC, float sD, float sE, float sF) {
#pragma unroll
    for (int s = 1; s <= 8; s <<= 1) {
#pragma unroll
        for (int m = 0; m < 16; ++m)
            if ((m & s) == 0) {
                float a = v[m], b = v[m ^ s];
                v[m] = a + b;
                v[m ^ s] = a - b;
            }
    }
#pragma unroll
    for (int m = 0; m < 16; ++m) { float o = dppmov<0xB1>(v[m]);  v[m] = fmaf(v[m], sA, o); } // xor 1
#pragma unroll
    for (int m = 0; m < 16; ++m) { float o = dppmov<0x4E>(v[m]);  v[m] = fmaf(v[m], sB, o); } // xor 2
#pragma unroll
    for (int m = 0; m < 16; ++m) { float o = dppmov<0x141>(v[m]); v[m] = fmaf(v[m], sC, o); } // xor 7
#pragma unroll
    for (int m = 0; m < 16; ++m) { float o = dppmov<0x140>(v[m]); v[m] = fmaf(v[m], sD, o); } // xor 15
#pragma unroll
    for (int m = 0; m < 16; ++m) { float o = __shfl_xor(v[m], 16, 64); v[m] = fmaf(v[m], sE, o); } // xor 16
#pragma unroll
    for (int m = 0; m < 16; ++m) { float o = __shfl_xor(v[m], 32, 64); v[m] = fmaf(v[m], sF, o); } // xor 32
}

// 16 batches/block, 512 threads, f32 64KB tile, 2 blocks/CU, ONE row live per
// wave at a time (v[16] only -> ~85 VGPR, no spills under the 128 cap).
__global__ __launch_bounds__(512, 4) void k_main(const float* __restrict__ x,
                                                 const float* __restrict__ s1,
                                                 const float* __restrict__ s2,
                                                 const float* __restrict__ u,
                                                 float* __restrict__ out) {
    __shared__ __align__(16) float tile[16 * 1024];
    const int t    = threadIdx.x;
    const int lane = t & 63;
    const int wv   = t >> 6;
    const int b0   = blockIdx.x * 16;   // 512 blocks

    const int l0 = lane & 1, l1 = (lane >> 1) & 1, l2 = (lane >> 2) & 1,
              l3 = (lane >> 3) & 1, l4 = (lane >> 4) & 1, l5 = (lane >> 5) & 1;
    const int hi = (l0 ^ l2) | ((l1 ^ l2) << 1) | ((l2 ^ l3) << 2) | (l3 << 3) |
                   (l4 << 4) | (l5 << 5);
    const int base = hi << 4;

    const float sA = (l0 ^ l2) ? -1.f : 1.f;
    const float sB = (l1 ^ l2) ? -1.f : 1.f;
    const float sC = (l2 ^ l3) ? -1.f : 1.f;
    const float sD = l3 ? -1.f : 1.f;
    const float sE = l4 ? -1.f : 1.f;
    const float sF = l5 ? -1.f : 1.f;

    float4 s2f[4], uf[4], s1f[4];
#pragma unroll
    for (int c = 0; c < 4; ++c) {
        s2f[c] = *(const float4*)(s2 + base + 4 * c);
        uf[c]  = *(const float4*)(u  + base + 4 * c);
        s1f[c] = *(const float4*)(s1 + base + 4 * c);
        const float kscale = 1.0f / 1024.0f;   // fold 1/D into s1
        s1f[c].x *= kscale; s1f[c].y *= kscale;
        s1f[c].z *= kscale; s1f[c].w *= kscale;
    }
    const int qsw = hi & 3;   // chunk-level swizzle (keeps 16B contiguity)

    for (int rr = 0; rr < 2; ++rr) {
        const int r = wv * 2 + rr;
        const float* xr = x + (size_t)(b0 + r) * DD + base;
        float v[16];
#pragma unroll
        for (int c = 0; c < 4; ++c) {
            float4 xv = *(const float4*)(xr + 4 * c);
            v[4 * c + 0] = xv.x * s2f[c].x;
            v[4 * c + 1] = xv.y * s2f[c].y;
            v[4 * c + 2] = xv.z * s2f[c].z;
            v[4 * c + 3] = xv.w * s2f[c].w;
        }
        fwht1024(v, sA, sB, sC, sD, sE, sF);
#pragma unroll
        for (int c = 0; c < 4; ++c) {
            v[4 * c + 0] *= uf[c].x;
            v[4 * c + 1] *= uf[c].y;
            v[4 * c + 2] *= uf[c].z;
            v[4 * c + 3] *= uf[c].w;
        }
        fwht1024(v, sA, sB, sC, sD, sE, sF);
        // tile word for (row r, feature d=hi*16+m):
        //   r*1024 + ((hi ^ ((r>>2)&3))<<4) + 4*((m>>2)^qsw(hi)) + (m&3)
        // -> 4x ds_write_b128 per row; <=2-way bank aliasing (free).
        float* trow = tile + r * 1024 + ((hi ^ ((r >> 2) & 3)) << 4);
#pragma unroll
        for (int c = 0; c < 4; ++c) {
            float4 y;
            y.x = fmaxf(v[4 * c + 0] * s1f[c].x, 0.f);
            y.y = fmaxf(v[4 * c + 1] * s1f[c].y, 0.f);
            y.z = fmaxf(v[4 * c + 2] * s1f[c].z, 0.f);
            y.w = fmaxf(v[4 * c + 3] * s1f[c].w, 0.f);
            *(float4*)(trow + 4 * (c ^ qsw)) = y;
        }
    }
    __syncthreads();

    // transposed store: thread t -> feature d=(t>>2)+it*128, batches r4..r4+3.
    // (r4+i)>>2 == t&3 for i<4, so the column offset is shared by all 4 reads.
#pragma unroll
    for (int it = 0; it < 8; ++it) {
        const int d  = (t >> 2) + (it << 7);
        const int r4 = (t & 3) << 2;
        const int h  = d >> 4;
        const int col = ((h ^ (t & 3)) << 4) + 4 * (((d >> 2) & 3) ^ (h & 3)) +
                        (d & 3);
        float4 y;
        y.x = tile[(r4 + 0) * 1024 + col];
        y.y = tile[(r4 + 1) * 1024 + col];
        y.z = tile[(r4 + 2) * 1024 + col];
        y.w = tile[(r4 + 3) * 1024 + col];
        *(float4*)(out + (size_t)d * BB + b0 + r4) = y;
    }
}

extern "C" void kernel_launch(void* const* d_in, const int* in_sizes, int n_in,
                              void* d_out, int out_size, void* d_ws, size_t ws_size,
                              hipStream_t stream) {
    const float* x   = (const float*)d_in[0];
    const float* s1  = (const float*)d_in[1];
    const float* s2  = (const float*)d_in[2];
    const float* mu  = (const float*)d_in[3];
    const float* rho = (const float*)d_in[4];
    const float* eps = (const float*)d_in[5];
    // d_in[6] = H unused: applied via fast Walsh-Hadamard transform.
    float* out = (float*)d_out;

    float* part = (float*)d_ws;      // [DD * 16] partials of t
    float* u    = part + DD * 16;    // [DD]

    k_t<<<256, 256, 0, stream>>>(rho, eps, part);
    k_u<<<DD, 256, 0, stream>>>(rho, mu, part, u);
    k_main<<<BB / 16, 512, 0, stream>>>(x, s1, s2, u, out);
}